// Round 2
// baseline (318.131 us; speedup 1.0000x reference)
//
#include <hip/hip_runtime.h>

typedef unsigned short u16;
typedef unsigned int   u32;
typedef float  f32x4  __attribute__((ext_vector_type(4)));
typedef __bf16 bf16x8 __attribute__((ext_vector_type(8)));
typedef u16    u16x8  __attribute__((ext_vector_type(8)));

#define NB     1024      // batch rows (M)
#define NN     8193      // output cols (N), true K = 8193
#define K2R    8256      // K padded to 129*64
#define NT     129       // K tiles of BK=64
#define ABF_LEN 16704    // a padded (true length 16385)
#define NFRAG  1042      // precomputed B-fragment blocks (1KB each)

// workspace byte offsets (256-aligned)
#define OFF_BANDS 0u          // 3*2049*4
#define OFF_BUF1  24832u      // 4097*4
#define OFF_BUF2  41472u      // 8193*4
#define OFF_ABF   74496u      // 16704*2 = 33408
#define OFF_BFRAG 108032u     // 1042*1024 = 1067008
#define OFF_UREV  1175040u    // 1024*8256*2 = 16908288  (total ~18.08 MB)

__device__ __forceinline__ u16 f2bf(float f) {
  u32 u = __builtin_bit_cast(u32, f);
  return (u16)((u + 0x7FFFu + ((u >> 16) & 1u)) >> 16);
}

// ---------------- kernel a construction ----------------
__global__ void k_bands(const float* __restrict__ x,
                        const float* __restrict__ W1, const float* __restrict__ b1,
                        const float* __restrict__ W2, const float* __restrict__ b2,
                        const float* __restrict__ W3, const float* __restrict__ b3,
                        float* __restrict__ bands) {
  const int j = blockIdx.y;
  __shared__ float w2s[4096];
  __shared__ float w1s[64], b1s[64], b2s[64], w3s[64];
  for (int i = threadIdx.x; i < 4096; i += 256) w2s[i] = W2[j * 4096 + i];
  if (threadIdx.x < 64) {
    w1s[threadIdx.x] = W1[j * 64 + threadIdx.x];
    b1s[threadIdx.x] = b1[j * 64 + threadIdx.x];
    b2s[threadIdx.x] = b2[j * 64 + threadIdx.x];
    w3s[threadIdx.x] = W3[j * 64 + threadIdx.x];
  }
  __syncthreads();
  const int k = blockIdx.x * 256 + threadIdx.x;
  if (k >= 2049) return;
  const float xc = x[8 * k];
  float h1[64];
  #pragma unroll
  for (int o = 0; o < 64; ++o) h1[o] = tanhf(w1s[o] * xc + b1s[o]);
  float outv = b3[j];
  for (int o = 0; o < 64; ++o) {
    float acc = b2s[o];
    #pragma unroll
    for (int c = 0; c < 64; ++c) acc += w2s[o * 64 + c] * h1[c];
    outv += w3s[o] * tanhf(acc);
  }
  bands[j * 2049 + k] = outv;
}

__global__ void k_lvl1(const float* __restrict__ bands, float* __restrict__ buf1) {
  const int i = blockIdx.x * 256 + threadIdx.x;
  if (i >= 4097) return;
  const float* bd0 = bands;
  const float* bd1 = bands + 2049;
  float v = (i & 1) ? 0.5f * (bd0[i >> 1] + bd0[(i >> 1) + 1]) : bd0[i >> 1];
  if (i >= 512 && i < 2561) v = bd1[i - 512];
  buf1[i] = v;
}

__global__ void k_lvl2(const float* __restrict__ bands, const float* __restrict__ buf1,
                       float* __restrict__ buf2) {
  const int i = blockIdx.x * 256 + threadIdx.x;
  if (i >= 8193) return;
  const float* bd2 = bands + 2 * 2049;
  float v = (i & 1) ? 0.5f * (buf1[i >> 1] + buf1[(i >> 1) + 1]) : buf1[i >> 1];
  if (i >= 1024 && i < 3073) v = bd2[i - 1024];
  buf2[i] = v;
}

__global__ void k_lvl3(const float* __restrict__ buf2, u16* __restrict__ abf) {
  const int i = blockIdx.x * 256 + threadIdx.x;
  if (i >= ABF_LEN) return;
  float v = 0.f;
  if (i <= 16384)
    v = (i & 1) ? 0.5f * (buf2[i >> 1] + buf2[(i >> 1) + 1]) : buf2[i >> 1];
  abf[i] = f2bf(v);
}

// urev[b][j] = bf16(u[b][8192-j]) for j<=8192 else 0 (row stride K2R)
__global__ void k_urev(const float* __restrict__ u, u16* __restrict__ urev) {
  const long total = (long)NB * (K2R / 8);
  for (long c = (long)blockIdx.x * 256 + threadIdx.x; c < total;
       c += (long)gridDim.x * 256) {
    const int b = (int)(c / (K2R / 8));
    const int j = (int)(c % (K2R / 8)) * 8;
    u16x8 v;
    #pragma unroll
    for (int r = 0; r < 8; ++r) {
      const int jr = j + r;
      const float f = (jr <= 8192) ? u[(size_t)b * NN + 8192 - jr] : 0.f;
      v[r] = f2bf(f);
    }
    *(u16x8*)&urev[(size_t)b * K2R + j] = v;
  }
}

// Bfrag[t][lane][idx] = abf[16t + (lane&15) + 8*(lane>>4) + idx]
__global__ void k_bfrag(const u16* __restrict__ abf, u16* __restrict__ bfr) {
  const int g = blockIdx.x * 256 + threadIdx.x;
  if (g >= NFRAG * 64) return;
  const int t = g >> 6, l = g & 63;
  const int s = 16 * t + (l & 15) + ((l >> 4) << 3);
  u16x8 v;
  #pragma unroll
  for (int r = 0; r < 8; ++r) v[r] = abf[s + r];
  *(u16x8*)&bfr[(size_t)g * 8] = v;
}

// ---------------- main Hankel GEMM ----------------
// BM=128 x BN=256 x BK=64, 512 threads (8 waves, 2Mx4N), A in LDS (swizzled),
// B fragments direct L2->reg, counted-vmcnt pipeline.
__device__ __forceinline__ void gload16(const void* g, void* l) {
  __builtin_amdgcn_global_load_lds((__attribute__((address_space(1))) void*)(void*)g,
                                   (__attribute__((address_space(3))) void*)l, 16, 0, 0);
}

__global__ __launch_bounds__(512, 2) void k_gemm(const u16* __restrict__ urev,
                                                 const u16* __restrict__ bfrag,
                                                 float* __restrict__ out) {
  __shared__ u16 Ab[2][8192];  // [128 rows][64 k] bf16, 16KB per buffer
  const int tid  = threadIdx.x;
  const int lane = tid & 63;
  const int wid  = tid >> 6;
  const int wr   = wid >> 2;   // 0..1  (64-row slice)
  const int wc   = wid & 3;    // 0..3  (64-col slice)

  // bijective XCD swizzle: 264 blocks, 8 XCDs -> each XCD one by-stripe
  int bid = (blockIdx.x & 7) * 33 + (blockIdx.x >> 3);
  const int by = bid / 33, bx = bid % 33;
  const int b0 = by * 128;
  const int i0 = bx * 256;
  const int F0 = bx * 16;      // base fragment index

  // A staging: 1024 x 16B chunks; chunk ch=(row, slot s), source slot = s ^ (row&7)
  const int ch0 = tid, ch1 = tid + 512;
  const u16* aSrc0 = urev + (size_t)(b0 + (ch0 >> 3)) * K2R + (((ch0 & 7) ^ ((ch0 >> 3) & 7)) << 3);
  const u16* aSrc1 = urev + (size_t)(b0 + (ch1 >> 3)) * K2R + (((ch1 & 7) ^ ((ch1 >> 3) & 7)) << 3);

  f32x4 acc[4][4] = {};
  bf16x8 af[8];
  bf16x8 nbA[6], nbB[6];
  const u16* bPtr = bfrag + (((size_t)(F0 + (wc << 2))) << 9) + (lane << 3);

  auto stage = [&](int buf, int t) {
    const int j0 = t << 6;
    gload16(aSrc0 + j0, &Ab[buf][ch0 << 3]);
    gload16(aSrc1 + j0, &Ab[buf][ch1 << 3]);
  };
  auto bload = [&](bf16x8* nb) {
    #pragma unroll
    for (int j = 0; j < 6; ++j)
      nb[j] = *reinterpret_cast<const bf16x8*>(bPtr + (j << 9));
    bPtr += (4 << 9);
  };
  auto lda = [&](int buf) {
    #pragma unroll
    for (int kk = 0; kk < 2; ++kk)
      #pragma unroll
      for (int m = 0; m < 4; ++m) {
        const int row  = (wr << 6) + (m << 4) + (lane & 15);
        const int slot = ((lane >> 4) + (kk << 2)) ^ (row & 7);
        af[(kk << 2) + m] = *reinterpret_cast<const bf16x8*>(&Ab[buf][(row << 6) + (slot << 3)]);
      }
  };
  auto mm = [&](const bf16x8* nb) {
    #pragma unroll
    for (int kk = 0; kk < 2; ++kk)
      #pragma unroll
      for (int m = 0; m < 4; ++m)
        #pragma unroll
        for (int n = 0; n < 4; ++n)
          acc[m][n] = __builtin_amdgcn_mfma_f32_16x16x32_bf16(
              af[(kk << 2) + m], nb[n + (kk << 1)], acc[m][n], 0, 0, 0);
  };

#define ITER(bc, bn, nbU, nbF, tt)                                        \
  {                                                                       \
    stage(bn, (tt) + 1);                                                  \
    __builtin_amdgcn_sched_barrier(0);                                    \
    bload(nbF);                                                           \
    __builtin_amdgcn_sched_barrier(0);                                    \
    lda(bc);                                                              \
    asm volatile("s_waitcnt vmcnt(8) lgkmcnt(0)" ::: "memory");           \
    __builtin_amdgcn_sched_barrier(0);                                    \
    __builtin_amdgcn_s_setprio(1);                                        \
    mm(nbU);                                                              \
    __builtin_amdgcn_s_setprio(0);                                        \
    __builtin_amdgcn_sched_barrier(0);                                    \
    asm volatile("s_waitcnt vmcnt(6)" ::: "memory");                      \
    __builtin_amdgcn_s_barrier();                                         \
  }

  // prologue: tile 0
  stage(0, 0);
  __builtin_amdgcn_sched_barrier(0);
  bload(nbA);
  asm volatile("s_waitcnt vmcnt(6)" ::: "memory");
  __builtin_amdgcn_s_barrier();

  #pragma unroll 1
  for (int t = 0; t < NT - 1; t += 2) {
    ITER(0, 1, nbA, nbB, t);
    ITER(1, 0, nbB, nbA, t + 1);
  }

  // epilogue: tile NT-1 in buf 0 / nbA
  lda(0);
  asm volatile("s_waitcnt vmcnt(0) lgkmcnt(0)" ::: "memory");
  __builtin_amdgcn_sched_barrier(0);
  mm(nbA);
#undef ITER

  #pragma unroll
  for (int n = 0; n < 4; ++n) {
    const int col = i0 + (wc << 6) + (n << 4) + (lane & 15);
    if (col < NN) {
      #pragma unroll
      for (int m = 0; m < 4; ++m) {
        const int rowb = b0 + (wr << 6) + (m << 4) + ((lane >> 4) << 2);
        float* o = out + (size_t)rowb * NN + col;
        #pragma unroll
        for (int r = 0; r < 4; ++r) o[(size_t)r * NN] = acc[m][n][r];
      }
    }
  }
}

extern "C" void kernel_launch(void* const* d_in, const int* in_sizes, int n_in,
                              void* d_out, int out_size, void* d_ws, size_t ws_size,
                              hipStream_t stream) {
  (void)in_sizes; (void)n_in; (void)out_size; (void)ws_size;
  const float* u  = (const float*)d_in[0];
  const float* x  = (const float*)d_in[1];
  const float* W1 = (const float*)d_in[2];
  const float* b1 = (const float*)d_in[3];
  const float* W2 = (const float*)d_in[4];
  const float* b2 = (const float*)d_in[5];
  const float* W3 = (const float*)d_in[6];
  const float* b3 = (const float*)d_in[7];
  float* out = (float*)d_out;
  char*  ws  = (char*)d_ws;

  float* bands = (float*)(ws + OFF_BANDS);
  float* buf1  = (float*)(ws + OFF_BUF1);
  float* buf2  = (float*)(ws + OFF_BUF2);
  u16*   abf   = (u16*)(ws + OFF_ABF);
  u16*   bfr   = (u16*)(ws + OFF_BFRAG);
  u16*   urev  = (u16*)(ws + OFF_UREV);

  k_bands<<<dim3(9, 3), 256, 0, stream>>>(x, W1, b1, W2, b2, W3, b3, bands);
  k_lvl1<<<17, 256, 0, stream>>>(bands, buf1);
  k_lvl2<<<33, 256, 0, stream>>>(bands, buf1, buf2);
  k_lvl3<<<66, 256, 0, stream>>>(buf2, abf);
  k_urev<<<2048, 256, 0, stream>>>(u, urev);
  k_bfrag<<<261, 256, 0, stream>>>(abf, bfr);
  k_gemm<<<264, 512, 0, stream>>>(urev, bfr, out);
}

// Round 4
// 219.884 us; speedup vs baseline: 1.4468x; 1.4468x over previous
//
#include <hip/hip_runtime.h>

typedef unsigned short u16;
typedef unsigned int   u32;
typedef float  f32x4  __attribute__((ext_vector_type(4)));
typedef __bf16 bf16x8 __attribute__((ext_vector_type(8)));
typedef u16    u16x8  __attribute__((ext_vector_type(8)));

#define NB     1024      // batch rows (M)
#define NN     8193      // output cols; true K = 8193
#define K2R    8256      // K padded to 129*64
#define NT     129       // K tiles of BK=64
#define ABF_LEN 16704    // a padded (true length 16385)
#define NFRAG  1032      // 16-wide Hankel fragment blocks (1KB each)

// workspace byte offsets (256-aligned)
#define OFF_BANDS 0u
#define OFF_BUF1  24832u
#define OFF_BUF2  41472u
#define OFF_ABF   74496u      // 16704*2 = 33408
#define OFF_BFRAG 108032u     // 1032*1024
#define OFF_UREV  1175040u    // 1024*8256*2

__device__ __forceinline__ u16 f2bf(float f) {
  u32 u = __builtin_bit_cast(u32, f);
  return (u16)((u + 0x7FFFu + ((u >> 16) & 1u)) >> 16);
}
__device__ __forceinline__ float bf2f(u16 h) {
  u32 u = ((u32)h) << 16;
  return __builtin_bit_cast(float, u);
}

// ---------------- kernel a construction ----------------
__global__ void k_bands(const float* __restrict__ x,
                        const float* __restrict__ W1, const float* __restrict__ b1,
                        const float* __restrict__ W2, const float* __restrict__ b2,
                        const float* __restrict__ W3, const float* __restrict__ b3,
                        float* __restrict__ bands) {
  const int j = blockIdx.y;
  __shared__ float w2s[4096];
  __shared__ float w1s[64], b1s[64], b2s[64], w3s[64];
  for (int i = threadIdx.x; i < 4096; i += 256) w2s[i] = W2[j * 4096 + i];
  if (threadIdx.x < 64) {
    w1s[threadIdx.x] = W1[j * 64 + threadIdx.x];
    b1s[threadIdx.x] = b1[j * 64 + threadIdx.x];
    b2s[threadIdx.x] = b2[j * 64 + threadIdx.x];
    w3s[threadIdx.x] = W3[j * 64 + threadIdx.x];
  }
  __syncthreads();
  const int k = blockIdx.x * 256 + threadIdx.x;
  if (k >= 2049) return;
  const float xc = x[8 * k];
  float h1[64];
  #pragma unroll
  for (int o = 0; o < 64; ++o) h1[o] = tanhf(w1s[o] * xc + b1s[o]);
  float outv = b3[j];
  for (int o = 0; o < 64; ++o) {
    float acc = b2s[o];
    #pragma unroll
    for (int c = 0; c < 64; ++c) acc += w2s[o * 64 + c] * h1[c];
    outv += w3s[o] * tanhf(acc);
  }
  bands[j * 2049 + k] = outv;
}

__global__ void k_lvl1(const float* __restrict__ bands, float* __restrict__ buf1) {
  const int i = blockIdx.x * 256 + threadIdx.x;
  if (i >= 4097) return;
  const float* bd0 = bands;
  const float* bd1 = bands + 2049;
  float v = (i & 1) ? 0.5f * (bd0[i >> 1] + bd0[(i >> 1) + 1]) : bd0[i >> 1];
  if (i >= 512 && i < 2561) v = bd1[i - 512];
  buf1[i] = v;
}

__global__ void k_lvl2(const float* __restrict__ bands, const float* __restrict__ buf1,
                       float* __restrict__ buf2) {
  const int i = blockIdx.x * 256 + threadIdx.x;
  if (i >= 8193) return;
  const float* bd2 = bands + 2 * 2049;
  float v = (i & 1) ? 0.5f * (buf1[i >> 1] + buf1[(i >> 1) + 1]) : buf1[i >> 1];
  if (i >= 1024 && i < 3073) v = bd2[i - 1024];
  buf2[i] = v;
}

__global__ void k_lvl3(const float* __restrict__ buf2, u16* __restrict__ abf) {
  const int i = blockIdx.x * 256 + threadIdx.x;
  if (i >= ABF_LEN) return;
  float v = 0.f;
  if (i <= 16384)
    v = (i & 1) ? 0.5f * (buf2[i >> 1] + buf2[(i >> 1) + 1]) : buf2[i >> 1];
  abf[i] = f2bf(v);
}

// urev[b][j] = bf16(u[b][8192-j]) for j<=8192 else 0 (row stride K2R)
__global__ void k_urev(const float* __restrict__ u, u16* __restrict__ urev) {
  const long total = (long)NB * (K2R / 8);
  for (long c = (long)blockIdx.x * 256 + threadIdx.x; c < total;
       c += (long)gridDim.x * 256) {
    const int b = (int)(c / (K2R / 8));
    const int j = (int)(c % (K2R / 8)) * 8;
    u16x8 v;
    #pragma unroll
    for (int r = 0; r < 8; ++r) {
      const int jr = j + r;
      const float f = (jr <= 8192) ? u[(size_t)b * NN + 8192 - jr] : 0.f;
      v[r] = f2bf(f);
    }
    *(u16x8*)&urev[(size_t)b * K2R + j] = v;
  }
}

// 16-wide Hankel fragments (round-1 proven) for mfma_16x16x32 B-operand:
// Bfrag[t][lane][idx] = abf[16t + (lane&15) + 8*(lane>>4) + idx]
__global__ void k_bfrag(const u16* __restrict__ abf, u16* __restrict__ bfr) {
  const int g = blockIdx.x * 256 + threadIdx.x;
  if (g >= NFRAG * 64) return;
  const int t = g >> 6, l = g & 63;
  const int s = 16 * t + (l & 15) + ((l >> 4) << 3);
  u16x8 v;
  #pragma unroll
  for (int r = 0; r < 8; ++r) v[r] = abf[s + r];
  *(u16x8*)&bfr[(size_t)g * 8] = v;
}

// column 8192: w[b,8192] = sum_j urev[b,j] * abf[8192+j]
__global__ void k_lastcol(const u16* __restrict__ urev, const u16* __restrict__ abf,
                          float* __restrict__ out) {
  const int b = blockIdx.x;
  const int tid = threadIdx.x;
  float s = 0.f;
  #pragma unroll
  for (int it = 0; it < 5; ++it) {
    const int c = tid + 256 * it;
    if (c < K2R / 8) {
      u16x8 uv = *(const u16x8*)&urev[(size_t)b * K2R + c * 8];
      u16x8 av = *(const u16x8*)&abf[8192 + c * 8];
      #pragma unroll
      for (int r = 0; r < 8; ++r) s += bf2f(uv[r]) * bf2f(av[r]);
    }
  }
  #pragma unroll
  for (int off = 32; off >= 1; off >>= 1) s += __shfl_xor(s, off, 64);
  __shared__ float red[4];
  if ((tid & 63) == 0) red[tid >> 6] = s;
  __syncthreads();
  if (tid == 0) out[(size_t)b * NN + 8192] = red[0] + red[1] + red[2] + red[3];
}

// ---------------- main Hankel GEMM ----------------
// BM=128 x BN=256 x BK=64, 512 threads (8 waves, 2Mx4N), 16x16x32 MFMA.
// A in LDS (both-sides XOR swizzle), B staged in LDS as a 24-fragment window
// (dedup across waves), round-1-proven 2-phase schedule: stage-next ->
// compute-cur -> vmcnt(0) -> __syncthreads. Grid = 256 exactly (1 block/CU).
__device__ __forceinline__ void gload16(const void* g, void* l) {
  __builtin_amdgcn_global_load_lds((__attribute__((address_space(1))) void*)(void*)g,
                                   (__attribute__((address_space(3))) void*)l, 16, 0, 0);
}

__global__ __launch_bounds__(512, 2) void k_gemm(const u16* __restrict__ urev,
                                                 const u16* __restrict__ bfrag,
                                                 float* __restrict__ out) {
  __shared__ u16 Ab[2][8192];   // [128 rows][8 slots of 8 bf16], 16KB each
  __shared__ u16 Bb[2][12288];  // 24 fragment-KBs each
  const int tid  = threadIdx.x;
  const int lane = tid & 63;
  const int wid  = tid >> 6;
  const int wr   = wid >> 2;   // 0..1  (64-row slice)
  const int wc   = wid & 3;    // 0..3  (64-col slice)

  // 256 blocks: by = XCD id (round-robin), 32 bx share one A-panel per XCD
  const int by = blockIdx.x & 7;
  const int bx = blockIdx.x >> 3;
  const int b0 = by * 128;
  const int i0 = bx * 256;
  const int F0 = bx * 16;      // window base fragment at t=0

  // A staging: 1024 x 16B chunks; chunk = (row, slot), source slot = slot ^ (row&7)
  const int ch0 = tid, ch1 = tid + 512;
  const u16* aSrc0 = urev + (size_t)(b0 + (ch0 >> 3)) * K2R + (((ch0 & 7) ^ ((ch0 >> 3) & 7)) << 3);
  const u16* aSrc1 = urev + (size_t)(b0 + (ch1 >> 3)) * K2R + (((ch1 & 7) ^ ((ch1 >> 3) & 7)) << 3);
  // B staging: 1536 x 16B chunks (24 frags), 3 per thread; frag = ch>>6, lane = ch&63
  const u16* bSrc = bfrag + ((size_t)F0 << 9);

  f32x4 acc[4][4] = {};

  auto stage = [&](int buf, int t) {
    const int j0 = t << 6;
    gload16(aSrc0 + j0, &Ab[buf][ch0 << 3]);
    gload16(aSrc1 + j0, &Ab[buf][ch1 << 3]);
    const u16* bs = bSrc + ((size_t)(t << 2) << 9);  // window base F0 + 4t
    #pragma unroll
    for (int r = 0; r < 3; ++r) {
      const int ch = tid + (r << 9);
      gload16(bs + (ch << 3), &Bb[buf][ch << 3]);
    }
  };

  auto compute = [&](int buf) {
    bf16x8 af[8], bfv[8];
    #pragma unroll
    for (int kk = 0; kk < 2; ++kk)
      #pragma unroll
      for (int m = 0; m < 4; ++m) {
        const int row  = (wr << 6) + (m << 4) + (lane & 15);
        const int slot = ((lane >> 4) + (kk << 2)) ^ (row & 7);
        af[(kk << 2) + m] = *reinterpret_cast<const bf16x8*>(&Ab[buf][(row << 6) + (slot << 3)]);
      }
    #pragma unroll
    for (int kk = 0; kk < 2; ++kk)
      #pragma unroll
      for (int n = 0; n < 4; ++n) {
        const int w = (wc << 2) + n + (kk << 1);   // window frag index, 0..17
        bfv[(kk << 2) + n] = *reinterpret_cast<const bf16x8*>(&Bb[buf][(w << 9) + (lane << 3)]);
      }
    #pragma unroll
    for (int kk = 0; kk < 2; ++kk)
      #pragma unroll
      for (int m = 0; m < 4; ++m)
        #pragma unroll
        for (int n = 0; n < 4; ++n)
          acc[m][n] = __builtin_amdgcn_mfma_f32_16x16x32_bf16(
              af[(kk << 2) + m], bfv[(kk << 2) + n], acc[m][n], 0, 0, 0);
  };

  // prologue
  stage(0, 0);
  asm volatile("s_waitcnt vmcnt(0)" ::: "memory");
  __syncthreads();
  int cur = 0;
  #pragma unroll 1
  for (int t = 0; t < NT - 1; ++t) {
    stage(cur ^ 1, t + 1);
    compute(cur);
    asm volatile("s_waitcnt vmcnt(0)" ::: "memory");
    __syncthreads();
    cur ^= 1;
  }
  compute(cur);

  // C-write (round-1 proven 16x16 layout): col = lane&15 (+16n), row = 4*(lane>>4)+r
  #pragma unroll
  for (int n = 0; n < 4; ++n) {
    const int col = i0 + (wc << 6) + (n << 4) + (lane & 15);
    #pragma unroll
    for (int m = 0; m < 4; ++m) {
      const int rowb = b0 + (wr << 6) + (m << 4) + ((lane >> 4) << 2);
      float* o = out + (size_t)rowb * NN + col;
      #pragma unroll
      for (int r = 0; r < 4; ++r) o[(size_t)r * NN] = acc[m][n][r];
    }
  }
}

extern "C" void kernel_launch(void* const* d_in, const int* in_sizes, int n_in,
                              void* d_out, int out_size, void* d_ws, size_t ws_size,
                              hipStream_t stream) {
  (void)in_sizes; (void)n_in; (void)out_size; (void)ws_size;
  const float* u  = (const float*)d_in[0];
  const float* x  = (const float*)d_in[1];
  const float* W1 = (const float*)d_in[2];
  const float* b1 = (const float*)d_in[3];
  const float* W2 = (const float*)d_in[4];
  const float* b2 = (const float*)d_in[5];
  const float* W3 = (const float*)d_in[6];
  const float* b3 = (const float*)d_in[7];
  float* out = (float*)d_out;
  char*  ws  = (char*)d_ws;

  float* bands = (float*)(ws + OFF_BANDS);
  float* buf1  = (float*)(ws + OFF_BUF1);
  float* buf2  = (float*)(ws + OFF_BUF2);
  u16*   abf   = (u16*)(ws + OFF_ABF);
  u16*   bfr   = (u16*)(ws + OFF_BFRAG);
  u16*   urev  = (u16*)(ws + OFF_UREV);

  k_bands<<<dim3(9, 3), 256, 0, stream>>>(x, W1, b1, W2, b2, W3, b3, bands);
  k_lvl1<<<17, 256, 0, stream>>>(bands, buf1);
  k_lvl2<<<33, 256, 0, stream>>>(bands, buf1, buf2);
  k_lvl3<<<66, 256, 0, stream>>>(buf2, abf);
  k_urev<<<2048, 256, 0, stream>>>(u, urev);
  k_bfrag<<<258, 256, 0, stream>>>(abf, bfr);
  k_lastcol<<<1024, 256, 0, stream>>>(urev, abf, out);
  k_gemm<<<256, 512, 0, stream>>>(urev, bfr, out);
}